// Round 1
// baseline (3236.032 us; speedup 1.0000x reference)
//
#include <hip/hip_runtime.h>

#define B_ 4
#define S_ 1024
#define D_ 1024
#define H_ 16
#define DH_ 64

// ---------------------------------------------------------------------------
// GEMM: C[M,N] = A[M,K] @ W[N,K]^T (+ bias[N]).  fp32, 128x128 tile, 8x8/thread.
// All five GEMMs in this problem are M=4096, N=1024, K=1024 (divisible by tiles).
// ---------------------------------------------------------------------------
#define BM 128
#define BN 128
#define BK 16
#define TM 8
#define TN 8

__global__ __launch_bounds__(256) void gemm_nt_bias(
    const float* __restrict__ A, const float* __restrict__ W,
    const float* __restrict__ bias, float* __restrict__ C,
    int M, int N, int K)
{
  __shared__ __align__(16) float As[BK][BM + 4];  // +4 pad: breaks bank conflicts, keeps 16B align
  __shared__ __align__(16) float Ws[BK][BN + 4];
  const int tid = threadIdx.x;
  const int tx = tid & 15;   // n-direction
  const int ty = tid >> 4;   // m-direction
  const int m0 = blockIdx.y * BM;
  const int n0 = blockIdx.x * BN;

  float acc[TM][TN];
#pragma unroll
  for (int i = 0; i < TM; ++i)
#pragma unroll
    for (int j = 0; j < TN; ++j) acc[i][j] = 0.f;

  for (int k0 = 0; k0 < K; k0 += BK) {
    // Stage A tile (128 rows x 16 k) and W tile, transposed into LDS as [k][m].
#pragma unroll
    for (int r = 0; r < 2; ++r) {
      const int f = tid + 256 * r;      // 0..511 float4 slots
      const int row = f >> 2;           // 0..127
      const int c4 = (f & 3) << 2;      // k offset 0,4,8,12
      float4 av = *(const float4*)(A + (size_t)(m0 + row) * K + k0 + c4);
      As[c4 + 0][row] = av.x;
      As[c4 + 1][row] = av.y;
      As[c4 + 2][row] = av.z;
      As[c4 + 3][row] = av.w;
      float4 wv = *(const float4*)(W + (size_t)(n0 + row) * K + k0 + c4);
      Ws[c4 + 0][row] = wv.x;
      Ws[c4 + 1][row] = wv.y;
      Ws[c4 + 2][row] = wv.z;
      Ws[c4 + 3][row] = wv.w;
    }
    __syncthreads();
#pragma unroll
    for (int kk = 0; kk < BK; ++kk) {
      float a[TM], w[TN];
      *(float4*)&a[0] = *(const float4*)&As[kk][ty * TM];
      *(float4*)&a[4] = *(const float4*)&As[kk][ty * TM + 4];
      *(float4*)&w[0] = *(const float4*)&Ws[kk][tx * TN];
      *(float4*)&w[4] = *(const float4*)&Ws[kk][tx * TN + 4];
#pragma unroll
      for (int i = 0; i < TM; ++i)
#pragma unroll
        for (int j = 0; j < TN; ++j) acc[i][j] = fmaf(a[i], w[j], acc[i][j]);
    }
    __syncthreads();
  }

#pragma unroll
  for (int i = 0; i < TM; ++i) {
    float* cp = C + (size_t)(m0 + ty * TM + i) * N + n0 + tx * TN;
#pragma unroll
    for (int j = 0; j < TN; j += 4) {
      float4 v;
      v.x = acc[i][j + 0];
      v.y = acc[i][j + 1];
      v.z = acc[i][j + 2];
      v.w = acc[i][j + 3];
      if (bias) {
        v.x += bias[n0 + tx * TN + j + 0];
        v.y += bias[n0 + tx * TN + j + 1];
        v.z += bias[n0 + tx * TN + j + 2];
        v.w += bias[n0 + tx * TN + j + 3];
      }
      *(float4*)(cp + j) = v;
    }
  }
}

// ---------------------------------------------------------------------------
// Per-batch valid length: L = S - sum_i mask[b, i, 0]   (mask as int32)
// ---------------------------------------------------------------------------
__global__ void len_kernel(const int* __restrict__ mask, int* __restrict__ len)
{
  const int b = blockIdx.x;
  int cnt = 0;
  for (int i = threadIdx.x; i < S_; i += 256)
    cnt += (mask[(size_t)b * S_ * S_ + (size_t)i * S_] != 0) ? 1 : 0;
  __shared__ int sh[256];
  sh[threadIdx.x] = cnt;
  __syncthreads();
  for (int off = 128; off > 0; off >>= 1) {
    if (threadIdx.x < off) sh[threadIdx.x] += sh[threadIdx.x + off];
    __syncthreads();
  }
  if (threadIdx.x == 0) len[b] = S_ - sh[0];
}

// ---------------------------------------------------------------------------
// Attention core. One wave (64 lanes) per (b, h, query row i); lane = head dim.
// Online softmax over j < L with the relative-shift pos term computed inline:
//   j <= i   : pos = (q_i + v_bias) . p[L-1-i+j]
//   j == i+1 : pos = 0
//   j >= i+2 : pos = (q_{i+1} + v_bias) . p[j-i-2]
// Masked columns (j >= L) contribute exp(-10000-max) == 0.0f exactly -> skipped.
// Rows i >= L produce exactly 0 context (matches reference attn-zeroing).
// ---------------------------------------------------------------------------
__global__ __launch_bounds__(64) void attn_kernel(
    const float* __restrict__ Q, const float* __restrict__ Kt,
    const float* __restrict__ V, const float* __restrict__ P,
    const float* __restrict__ u_bias, const float* __restrict__ v_bias,
    const int* __restrict__ len, float* __restrict__ CTX)
{
  const int i = blockIdx.x;
  const int h = blockIdx.y;
  const int b = blockIdx.z;
  const int lane = threadIdx.x;
  const int L = len[b];
  const size_t outIdx = ((size_t)b * S_ + i) * D_ + h * DH_ + lane;
  if (i >= L) { CTX[outIdx] = 0.f; return; }

  const size_t base = (size_t)b * S_ * D_ + h * DH_ + lane;  // + j*D_
  const float ub = u_bias[h * DH_ + lane];
  const float vb = v_bias[h * DH_ + lane];
  const float qi = Q[base + (size_t)i * D_];
  const float qu = qi + ub;
  const float qv = qi + vb;
  const float qvn = (i + 1 < S_) ? (Q[base + (size_t)(i + 1) * D_] + vb) : 0.f;

  float m = -3.0e38f, l = 0.f, ctx = 0.f;
  for (int j = 0; j < L; ++j) {
    const float kv = Kt[base + (size_t)j * D_];
    float pv = 0.f, qq = 0.f;
    if (j <= i) {                 // wave-uniform branches (i, j same across lanes)
      pv = P[base + (size_t)(L - 1 - i + j) * D_];
      qq = qv;
    } else if (j >= i + 2) {
      pv = P[base + (size_t)(j - i - 2) * D_];
      qq = qvn;
    }
    float part = qu * kv + qq * pv;
#pragma unroll
    for (int off = 32; off > 0; off >>= 1) part += __shfl_xor(part, off, 64);
    const float s = part * (1.0f / 32.0f);   // / sqrt(1024)

    const float mn = fmaxf(m, s);
    const float alpha = __expf(m - mn);
    const float p = __expf(s - mn);
    l = l * alpha + p;
    const float vv = V[base + (size_t)j * D_];
    ctx = ctx * alpha + p * vv;
    m = mn;
  }
  CTX[outIdx] = ctx / l;
}

// ---------------------------------------------------------------------------
extern "C" void kernel_launch(void* const* d_in, const int* in_sizes, int n_in,
                              void* d_out, int out_size, void* d_ws, size_t ws_size,
                              hipStream_t stream)
{
  (void)in_sizes; (void)n_in; (void)out_size;
  const float* query = (const float*)d_in[0];
  const float* key   = (const float*)d_in[1];
  const float* value = (const float*)d_in[2];
  const float* pos   = (const float*)d_in[3];
  const float* Wq    = (const float*)d_in[4];
  const float* bq    = (const float*)d_in[5];
  const float* Wk    = (const float*)d_in[6];
  const float* bk    = (const float*)d_in[7];
  const float* Wv    = (const float*)d_in[8];
  const float* bv    = (const float*)d_in[9];
  const float* Wpos  = (const float*)d_in[10];
  const float* ub    = (const float*)d_in[11];
  const float* vb    = (const float*)d_in[12];
  const float* Wout  = (const float*)d_in[13];
  const float* bout  = (const float*)d_in[14];
  const int*   mask  = (const int*)d_in[15];

  const size_t TENS = (size_t)B_ * S_ * D_;   // 4,194,304 floats
  float* ws = (float*)d_ws;
  float* Q   = ws + 0 * TENS;
  float* Kp  = ws + 1 * TENS;
  float* V   = ws + 2 * TENS;
  float* P   = ws + 3 * TENS;
  float* CTX = ws + 4 * TENS;
  int*   len = (int*)(ws + 5 * TENS);
  if (ws_size < (5 * TENS + 16) * sizeof(float)) return;  // need ~80 MiB

  const int M = B_ * S_;  // 4096

  len_kernel<<<dim3(B_), dim3(256), 0, stream>>>(mask, len);

  dim3 gblk(256);
  dim3 ggrid(D_ / BN, M / BM);  // (8, 32)
  gemm_nt_bias<<<ggrid, gblk, 0, stream>>>(query, Wq, bq, Q, M, D_, D_);
  gemm_nt_bias<<<ggrid, gblk, 0, stream>>>(key,   Wk, bk, Kp, M, D_, D_);
  gemm_nt_bias<<<ggrid, gblk, 0, stream>>>(value, Wv, bv, V, M, D_, D_);
  gemm_nt_bias<<<ggrid, gblk, 0, stream>>>(pos,   Wpos, nullptr, P, M, D_, D_);

  attn_kernel<<<dim3(S_, H_, B_), dim3(64), 0, stream>>>(Q, Kp, V, P, ub, vb, len, CTX);

  gemm_nt_bias<<<ggrid, gblk, 0, stream>>>(CTX, Wout, bout, (float*)d_out, M, D_, D_);
}

// Round 2
// 1863.378 us; speedup vs baseline: 1.7366x; 1.7366x over previous
//
#include <hip/hip_runtime.h>

#define B_ 4
#define S_ 1024
#define D_ 1024
#define H_ 16
#define DH_ 64
#define NEG_BIG -1.0e30f

// ---------------------------------------------------------------------------
// GEMM: C[M,N] = A[M,K] @ W[N,K]^T (+ bias[N]).  fp32, 128x128 tile, 8x8/thread.
// ---------------------------------------------------------------------------
#define BM 128
#define BN 128
#define BK 16
#define TM 8
#define TN 8

__global__ __launch_bounds__(256) void gemm_nt_bias(
    const float* __restrict__ A, const float* __restrict__ W,
    const float* __restrict__ bias, float* __restrict__ C,
    int M, int N, int K)
{
  __shared__ __align__(16) float As[BK][BM + 4];
  __shared__ __align__(16) float Ws[BK][BN + 4];
  const int tid = threadIdx.x;
  const int tx = tid & 15;
  const int ty = tid >> 4;
  const int m0 = blockIdx.y * BM;
  const int n0 = blockIdx.x * BN;

  float acc[TM][TN];
#pragma unroll
  for (int i = 0; i < TM; ++i)
#pragma unroll
    for (int j = 0; j < TN; ++j) acc[i][j] = 0.f;

  for (int k0 = 0; k0 < K; k0 += BK) {
#pragma unroll
    for (int r = 0; r < 2; ++r) {
      const int f = tid + 256 * r;
      const int row = f >> 2;
      const int c4 = (f & 3) << 2;
      float4 av = *(const float4*)(A + (size_t)(m0 + row) * K + k0 + c4);
      As[c4 + 0][row] = av.x;
      As[c4 + 1][row] = av.y;
      As[c4 + 2][row] = av.z;
      As[c4 + 3][row] = av.w;
      float4 wv = *(const float4*)(W + (size_t)(n0 + row) * K + k0 + c4);
      Ws[c4 + 0][row] = wv.x;
      Ws[c4 + 1][row] = wv.y;
      Ws[c4 + 2][row] = wv.z;
      Ws[c4 + 3][row] = wv.w;
    }
    __syncthreads();
#pragma unroll
    for (int kk = 0; kk < BK; ++kk) {
      float a[TM], w[TN];
      *(float4*)&a[0] = *(const float4*)&As[kk][ty * TM];
      *(float4*)&a[4] = *(const float4*)&As[kk][ty * TM + 4];
      *(float4*)&w[0] = *(const float4*)&Ws[kk][tx * TN];
      *(float4*)&w[4] = *(const float4*)&Ws[kk][tx * TN + 4];
#pragma unroll
      for (int i = 0; i < TM; ++i)
#pragma unroll
        for (int j = 0; j < TN; ++j) acc[i][j] = fmaf(a[i], w[j], acc[i][j]);
    }
    __syncthreads();
  }

#pragma unroll
  for (int i = 0; i < TM; ++i) {
    float* cp = C + (size_t)(m0 + ty * TM + i) * N + n0 + tx * TN;
#pragma unroll
    for (int j = 0; j < TN; j += 4) {
      float4 v;
      v.x = acc[i][j + 0];
      v.y = acc[i][j + 1];
      v.z = acc[i][j + 2];
      v.w = acc[i][j + 3];
      if (bias) {
        v.x += bias[n0 + tx * TN + j + 0];
        v.y += bias[n0 + tx * TN + j + 1];
        v.z += bias[n0 + tx * TN + j + 2];
        v.w += bias[n0 + tx * TN + j + 3];
      }
      *(float4*)(cp + j) = v;
    }
  }
}

// ---------------------------------------------------------------------------
__global__ void len_kernel(const int* __restrict__ mask, int* __restrict__ len)
{
  const int b = blockIdx.x;
  int cnt = 0;
  for (int i = threadIdx.x; i < S_; i += 256)
    cnt += (mask[(size_t)b * S_ * S_ + (size_t)i * S_] != 0) ? 1 : 0;
  __shared__ int sh[256];
  sh[threadIdx.x] = cnt;
  __syncthreads();
  for (int off = 128; off > 0; off >>= 1) {
    if (threadIdx.x < off) sh[threadIdx.x] += sh[threadIdx.x + off];
    __syncthreads();
  }
  if (threadIdx.x == 0) len[b] = S_ - sh[0];
}

// ---------------------------------------------------------------------------
// Tiled flash-style attention. Block = (b, h, 32 query rows), 256 threads.
// K/V/P staged in LDS as bf16; qu/qv and all accumulation fp32.
// Relative shift: for row i, key j:  dj = j - i
//   dj <= 0 : pos = (q_i   + v_bias) . p[L-1-i+j]   (window base A1)
//   dj == 1 : pos = 0  (falls out: P2 row r = -1 staged as zeros)
//   dj >= 2 : pos = (q_{i+1} + v_bias) . p[j-i-2]   (window base A2)
// Both map to local P row (TQ-1-il+jl).
// ---------------------------------------------------------------------------
#define TQ 32
#define TJ 64
#define KSTR 68   // ushort stride (bank-conflict pad, 8B-aligned rows)
#define QSTR 68   // float stride (16B-aligned rows)
#define SCSTR 65

__device__ __forceinline__ ushort f2bf(float x) {
  unsigned u = __float_as_uint(x);
  unsigned r = u + 0x7fffu + ((u >> 16) & 1u);
  return (ushort)(r >> 16);
}
__device__ __forceinline__ float4 bf4(const ushort* p) {
  ushort4 u = *(const ushort4*)p;
  float4 f;
  f.x = __uint_as_float(((unsigned)u.x) << 16);
  f.y = __uint_as_float(((unsigned)u.y) << 16);
  f.z = __uint_as_float(((unsigned)u.z) << 16);
  f.w = __uint_as_float(((unsigned)u.w) << 16);
  return f;
}
__device__ __forceinline__ float dot4(float4 a, float4 b) {
  return fmaf(a.x, b.x, fmaf(a.y, b.y, fmaf(a.z, b.z, a.w * b.w)));
}

__global__ __launch_bounds__(256) void attn_tiled(
    const float* __restrict__ Qf, const float* __restrict__ Kf,
    const float* __restrict__ Vf, const float* __restrict__ Pf,
    const float* __restrict__ ubias, const float* __restrict__ vbias,
    const int* __restrict__ len, float* __restrict__ CTX)
{
  __shared__ __align__(16) ushort Ks[TJ * KSTR];
  __shared__ __align__(16) ushort Vs[TJ * KSTR];
  __shared__ __align__(16) ushort P1s[(TJ + TQ) * KSTR];
  __shared__ __align__(16) ushort P2s[(TJ + TQ) * KSTR];
  __shared__ __align__(16) float qu[TQ * QSTR];
  __shared__ __align__(16) float qv[(TQ + 1) * QSTR];
  __shared__ __align__(16) float sc[TQ * SCSTR];
  __shared__ float mrow[TQ], lrow[TQ], arow[TQ];

  const int tid = threadIdx.x;
  const int i0 = blockIdx.x * TQ;
  const int h  = blockIdx.y;
  const int b  = blockIdx.z;
  const int L  = len[b];
  const size_t gb = ((size_t)b * S_) * D_ + h * DH_;  // + s*D_ + d

  if (i0 >= L) {  // fully masked tile -> zeros
    for (int idx = tid; idx < TQ * DH_; idx += 256) {
      int r = idx >> 6, d = idx & 63;
      CTX[gb + (size_t)(i0 + r) * D_ + d] = 0.f;
    }
    return;
  }

  // stage qu = q + u, qv = q + v (rows i0..i0+TQ, one extra qv row)
  for (int idx = tid; idx < TQ * DH_; idx += 256) {
    int r = idx >> 6, d = idx & 63;
    float q = Qf[gb + (size_t)(i0 + r) * D_ + d];
    qu[r * QSTR + d] = q + ubias[h * DH_ + d];
    qv[r * QSTR + d] = q + vbias[h * DH_ + d];
  }
  if (tid < DH_) {
    int gi = i0 + TQ;
    float q = (gi < S_) ? Qf[gb + (size_t)gi * D_ + tid] : 0.f;
    qv[TQ * QSTR + tid] = q + vbias[h * DH_ + tid];
  }
  if (tid < TQ) { mrow[tid] = NEG_BIG; lrow[tid] = 0.f; arow[tid] = 0.f; }

  // PV accumulator mapping: 2 rows x 4 dims per thread
  const int r0 = (tid >> 4) * 2;
  const int d4 = (tid & 15) * 4;
  float c0[4] = {0, 0, 0, 0}, c1[4] = {0, 0, 0, 0};

  // score micro-tile mapping: 2 rows x 4 cols per thread
  const int il0 = (tid >> 4) * 2;
  const int jl0 = (tid & 15) * 4;

  for (int j0 = 0; j0 < L; j0 += TJ) {
    __syncthreads();  // previous iteration's consumers done
    // --- stage K, V tiles (bf16) ---
    for (int idx = tid; idx < TJ * DH_; idx += 256) {
      int j = idx >> 6, d = idx & 63;
      int gj = j0 + j;
      float kv = 0.f, vv = 0.f;
      if (gj < S_) {
        kv = Kf[gb + (size_t)gj * D_ + d];
        vv = Vf[gb + (size_t)gj * D_ + d];
      }
      Ks[j * KSTR + d] = f2bf(kv);
      Vs[j * KSTR + d] = f2bf(vv);
    }
    // --- stage P windows ---
    const int A1 = L - TQ - i0 + j0;
    const int A2 = j0 - i0 - TQ - 1;
    for (int idx = tid; idx < (TJ + TQ) * DH_; idx += 256) {
      int p = idx >> 6, d = idx & 63;
      int r1 = A1 + p, r2 = A2 + p;
      float v1 = (r1 >= 0 && r1 < S_) ? Pf[gb + (size_t)r1 * D_ + d] : 0.f;
      float v2 = (r2 >= 0 && r2 < S_) ? Pf[gb + (size_t)r2 * D_ + d] : 0.f;
      P1s[p * KSTR + d] = f2bf(v1);
      P2s[p * KSTR + d] = f2bf(v2);
    }
    __syncthreads();

    // --- scores: 2x4 micro-tile per thread ---
    {
      float accC[2][4], accP[2][4];
      const ushort* pp[2][4];
      const int cc0 = i0 + il0 - j0 - jl0;  // branch1 iff jj <= cc(mi)
      const int cc1 = cc0 + 1;
#pragma unroll
      for (int mi = 0; mi < 2; ++mi) {
        const int cc = (mi == 0) ? cc0 : cc1;
#pragma unroll
        for (int jj = 0; jj < 4; ++jj) {
          int prow = TQ - 1 - (il0 + mi) + (jl0 + jj);
          pp[mi][jj] = ((jj <= cc) ? P1s : P2s) + prow * KSTR;
          accC[mi][jj] = 0.f;
          accP[mi][jj] = 0.f;
        }
      }
      for (int d = 0; d < DH_; d += 4) {
        float4 qa0 = *(const float4*)&qu[il0 * QSTR + d];
        float4 qa1 = *(const float4*)&qu[(il0 + 1) * QSTR + d];
        float4 qb0 = *(const float4*)&qv[il0 * QSTR + d];
        float4 qb1 = *(const float4*)&qv[(il0 + 1) * QSTR + d];
        float4 qb2 = *(const float4*)&qv[(il0 + 2) * QSTR + d];
#pragma unroll
        for (int jj = 0; jj < 4; ++jj) {
          float4 kf = bf4(&Ks[(jl0 + jj) * KSTR + d]);
          accC[0][jj] += dot4(qa0, kf);
          accC[1][jj] += dot4(qa1, kf);
          float4 pf0 = bf4(pp[0][jj] + d);
          float4 pf1 = bf4(pp[1][jj] + d);
          float4 qc0 = (jj <= cc0) ? qb0 : qb1;
          float4 qc1 = (jj <= cc1) ? qb1 : qb2;
          accP[0][jj] += dot4(qc0, pf0);
          accP[1][jj] += dot4(qc1, pf1);
        }
      }
#pragma unroll
      for (int mi = 0; mi < 2; ++mi)
#pragma unroll
        for (int jj = 0; jj < 4; ++jj) {
          int i = i0 + il0 + mi, j = j0 + jl0 + jj;
          float s = (accC[mi][jj] + accP[mi][jj]) * (1.f / 32.f);
          if (i >= L || j >= L) s = NEG_BIG;
          sc[(il0 + mi) * SCSTR + (jl0 + jj)] = s;
        }
    }
    __syncthreads();

    // --- softmax pass A: row max, alpha ---
    if (tid < TQ) {
      float mx = NEG_BIG;
      for (int jl = 0; jl < TJ; ++jl) mx = fmaxf(mx, sc[tid * SCSTR + jl]);
      float mold = mrow[tid];
      float mnew = fmaxf(mold, mx);
      arow[tid] = __expf(mold - mnew);
      mrow[tid] = mnew;
    }
    __syncthreads();
    // --- pass B: exponentiate in place ---
    for (int idx = tid; idx < TQ * TJ; idx += 256) {
      int il = idx >> 6, jl = idx & 63;
      sc[il * SCSTR + jl] = __expf(sc[il * SCSTR + jl] - mrow[il]);
    }
    __syncthreads();
    // --- pass C: row sums ---
    if (tid < TQ) {
      float s = 0.f;
      for (int jl = 0; jl < TJ; ++jl) s += sc[tid * SCSTR + jl];
      lrow[tid] = lrow[tid] * arow[tid] + s;
    }
    __syncthreads();

    // --- PV accumulate ---
    {
      float a0 = arow[r0], a1 = arow[r0 + 1];
#pragma unroll
      for (int q = 0; q < 4; ++q) { c0[q] *= a0; c1[q] *= a1; }
      for (int jl = 0; jl < TJ; ++jl) {
        float4 vv = bf4(&Vs[jl * KSTR + d4]);
        float p0 = sc[r0 * SCSTR + jl];
        float p1 = sc[(r0 + 1) * SCSTR + jl];
        c0[0] = fmaf(p0, vv.x, c0[0]);
        c0[1] = fmaf(p0, vv.y, c0[1]);
        c0[2] = fmaf(p0, vv.z, c0[2]);
        c0[3] = fmaf(p0, vv.w, c0[3]);
        c1[0] = fmaf(p1, vv.x, c1[0]);
        c1[1] = fmaf(p1, vv.y, c1[1]);
        c1[2] = fmaf(p1, vv.z, c1[2]);
        c1[3] = fmaf(p1, vv.w, c1[3]);
      }
    }
  }

  // epilogue: ctx / l, zero masked rows
  {
    int gi0 = i0 + r0, gi1 = gi0 + 1;
    float l0 = lrow[r0], l1 = lrow[r0 + 1];
    float inv0 = (gi0 < L && l0 > 0.f) ? 1.f / l0 : 0.f;
    float inv1 = (gi1 < L && l1 > 0.f) ? 1.f / l1 : 0.f;
    float4 o0, o1;
    o0.x = c0[0] * inv0; o0.y = c0[1] * inv0; o0.z = c0[2] * inv0; o0.w = c0[3] * inv0;
    o1.x = c1[0] * inv1; o1.y = c1[1] * inv1; o1.z = c1[2] * inv1; o1.w = c1[3] * inv1;
    *(float4*)&CTX[gb + (size_t)gi0 * D_ + d4] = o0;
    *(float4*)&CTX[gb + (size_t)gi1 * D_ + d4] = o1;
  }
}

// ---------------------------------------------------------------------------
extern "C" void kernel_launch(void* const* d_in, const int* in_sizes, int n_in,
                              void* d_out, int out_size, void* d_ws, size_t ws_size,
                              hipStream_t stream)
{
  (void)in_sizes; (void)n_in; (void)out_size;
  const float* query = (const float*)d_in[0];
  const float* key   = (const float*)d_in[1];
  const float* value = (const float*)d_in[2];
  const float* pos   = (const float*)d_in[3];
  const float* Wq    = (const float*)d_in[4];
  const float* bq    = (const float*)d_in[5];
  const float* Wk    = (const float*)d_in[6];
  const float* bk    = (const float*)d_in[7];
  const float* Wv    = (const float*)d_in[8];
  const float* bv    = (const float*)d_in[9];
  const float* Wpos  = (const float*)d_in[10];
  const float* ub    = (const float*)d_in[11];
  const float* vb    = (const float*)d_in[12];
  const float* Wout  = (const float*)d_in[13];
  const float* bout  = (const float*)d_in[14];
  const int*   mask  = (const int*)d_in[15];

  const size_t TENS = (size_t)B_ * S_ * D_;
  float* ws = (float*)d_ws;
  float* Q   = ws + 0 * TENS;
  float* Kp  = ws + 1 * TENS;
  float* V   = ws + 2 * TENS;
  float* P   = ws + 3 * TENS;
  float* CTX = ws + 4 * TENS;
  int*   len = (int*)(ws + 5 * TENS);
  if (ws_size < (5 * TENS + 16) * sizeof(float)) return;

  const int M = B_ * S_;

  len_kernel<<<dim3(B_), dim3(256), 0, stream>>>(mask, len);

  dim3 gblk(256);
  dim3 ggrid(D_ / BN, M / BM);
  gemm_nt_bias<<<ggrid, gblk, 0, stream>>>(query, Wq, bq, Q, M, D_, D_);
  gemm_nt_bias<<<ggrid, gblk, 0, stream>>>(key,   Wk, bk, Kp, M, D_, D_);
  gemm_nt_bias<<<ggrid, gblk, 0, stream>>>(value, Wv, bv, V, M, D_, D_);
  gemm_nt_bias<<<ggrid, gblk, 0, stream>>>(pos,   Wpos, nullptr, P, M, D_, D_);

  attn_tiled<<<dim3(S_ / TQ, H_, B_), dim3(256), 0, stream>>>(
      Q, Kp, V, P, ub, vb, len, CTX);

  gemm_nt_bias<<<ggrid, gblk, 0, stream>>>(CTX, Wout, bout, (float*)d_out, M, D_, D_);
}

// Round 3
// 1666.122 us; speedup vs baseline: 1.9423x; 1.1184x over previous
//
#include <hip/hip_runtime.h>

#define B_ 4
#define S_ 1024
#define D_ 1024
#define H_ 16
#define DH_ 64
#define OOS 0.03125f   // 1/sqrt(1024)

typedef __attribute__((ext_vector_type(8))) short short8;
typedef __attribute__((ext_vector_type(4))) float f32x4;

__device__ __forceinline__ ushort f2bf(float x) {
  unsigned u = __float_as_uint(x);
  unsigned r = u + 0x7fffu + ((u >> 16) & 1u);
  return (ushort)(r >> 16);
}

// ---------------------------------------------------------------------------
// GEMM: C[M,N] = A[M,K] @ W[N,K]^T (+ bias[N]).  fp32, 128x128 tile, 8x8/thread.
// ---------------------------------------------------------------------------
#define BM 128
#define BN 128
#define BK 16
#define TM 8
#define TN 8

__global__ __launch_bounds__(256) void gemm_nt_bias(
    const float* __restrict__ A, const float* __restrict__ W,
    const float* __restrict__ bias, float* __restrict__ C,
    int M, int N, int K)
{
  __shared__ __align__(16) float As[BK][BM + 4];
  __shared__ __align__(16) float Ws[BK][BN + 4];
  const int tid = threadIdx.x;
  const int tx = tid & 15;
  const int ty = tid >> 4;
  const int m0 = blockIdx.y * BM;
  const int n0 = blockIdx.x * BN;

  float acc[TM][TN];
#pragma unroll
  for (int i = 0; i < TM; ++i)
#pragma unroll
    for (int j = 0; j < TN; ++j) acc[i][j] = 0.f;

  for (int k0 = 0; k0 < K; k0 += BK) {
#pragma unroll
    for (int r = 0; r < 2; ++r) {
      const int f = tid + 256 * r;
      const int row = f >> 2;
      const int c4 = (f & 3) << 2;
      float4 av = *(const float4*)(A + (size_t)(m0 + row) * K + k0 + c4);
      As[c4 + 0][row] = av.x;
      As[c4 + 1][row] = av.y;
      As[c4 + 2][row] = av.z;
      As[c4 + 3][row] = av.w;
      float4 wv = *(const float4*)(W + (size_t)(n0 + row) * K + k0 + c4);
      Ws[c4 + 0][row] = wv.x;
      Ws[c4 + 1][row] = wv.y;
      Ws[c4 + 2][row] = wv.z;
      Ws[c4 + 3][row] = wv.w;
    }
    __syncthreads();
#pragma unroll
    for (int kk = 0; kk < BK; ++kk) {
      float a[TM], w[TN];
      *(float4*)&a[0] = *(const float4*)&As[kk][ty * TM];
      *(float4*)&a[4] = *(const float4*)&As[kk][ty * TM + 4];
      *(float4*)&w[0] = *(const float4*)&Ws[kk][tx * TN];
      *(float4*)&w[4] = *(const float4*)&Ws[kk][tx * TN + 4];
#pragma unroll
      for (int i = 0; i < TM; ++i)
#pragma unroll
        for (int j = 0; j < TN; ++j) acc[i][j] = fmaf(a[i], w[j], acc[i][j]);
    }
    __syncthreads();
  }

#pragma unroll
  for (int i = 0; i < TM; ++i) {
    float* cp = C + (size_t)(m0 + ty * TM + i) * N + n0 + tx * TN;
#pragma unroll
    for (int j = 0; j < TN; j += 4) {
      float4 v;
      v.x = acc[i][j + 0];
      v.y = acc[i][j + 1];
      v.z = acc[i][j + 2];
      v.w = acc[i][j + 3];
      if (bias) {
        v.x += bias[n0 + tx * TN + j + 0];
        v.y += bias[n0 + tx * TN + j + 1];
        v.z += bias[n0 + tx * TN + j + 2];
        v.w += bias[n0 + tx * TN + j + 3];
      }
      *(float4*)(cp + j) = v;
    }
  }
}

// ---------------------------------------------------------------------------
__global__ void len_kernel(const int* __restrict__ mask, int* __restrict__ len)
{
  const int b = blockIdx.x;
  int cnt = 0;
  for (int i = threadIdx.x; i < S_; i += 256)
    cnt += (mask[(size_t)b * S_ * S_ + (size_t)i * S_] != 0) ? 1 : 0;
  __shared__ int sh[256];
  sh[threadIdx.x] = cnt;
  __syncthreads();
  for (int off = 128; off > 0; off >>= 1) {
    if (threadIdx.x < off) sh[threadIdx.x] += sh[threadIdx.x + off];
    __syncthreads();
  }
  if (threadIdx.x == 0) len[b] = S_ - sh[0];
}

// ---------------------------------------------------------------------------
// MFMA flash attention. Block = (b, h, 32 query rows), 256 threads (4 waves).
// j-tiles of 64. Scores via mfma_f32_16x16x32_bf16:
//   content = Qu x K^T; pos = gather from G1 = Qv x P1^T, G2 = Qv(+1 row) x P2^T
// where P1/P2 are contiguous windows and selection is the pure column
// threshold c <= cthr (c = 31 - il + jl, cthr = 31 + i0 - j0); the j == i+1
// zero falls out of P2 row r2 = -1 staged as zeros.
// A/B frag: elem [lane&15][ (lane>>4)*8 + k ]; C/D: col=lane&15, row=quad*4+reg.
// ---------------------------------------------------------------------------
__global__ __launch_bounds__(256) void attn_mfma(
    const float* __restrict__ Qf, const float* __restrict__ Kf,
    const float* __restrict__ Vf, const float* __restrict__ Pf,
    const float* __restrict__ ubias, const float* __restrict__ vbias,
    const int* __restrict__ len, float* __restrict__ CTX)
{
  __shared__ __align__(16) ushort Qus[32 * 72];
  __shared__ __align__(16) ushort Qvs[33 * 72];
  __shared__ __align__(16) ushort Ks[64 * 72];
  __shared__ __align__(16) ushort Vts[64 * 72];      // V transposed [d][j]
  __shared__ __align__(16) char  UN[96 * 72 * 2 * 2]; // P1s+P2s | sc+Pb (27648 B)
  __shared__ float mrow[32], lrow[32], arow[32];

  ushort* const P1s = (ushort*)UN;
  ushort* const P2s = (ushort*)UN + 96 * 72;
  float*  const sc  = (float*)UN;                 // 32 x 68 fp32 (8704 B)
  ushort* const Pb  = (ushort*)(UN + 32 * 68 * 4); // 32 x 72 bf16 (4608 B)

  const int tid  = threadIdx.x;
  const int wave = tid >> 6, lane = tid & 63;
  const int m16  = lane & 15, quad = lane >> 4;
  const int mw   = wave & 1,  nw   = wave >> 1;
  const int koff0 = quad * 8;

  const int i0 = blockIdx.x * 32;
  const int h  = blockIdx.y;
  const int b  = blockIdx.z;
  const int L  = len[b];
  const size_t gb = ((size_t)b * S_) * D_ + h * DH_;

  if (i0 >= L) {
    for (int idx = tid; idx < 32 * 64; idx += 256) {
      const int r = idx >> 6, d = idx & 63;
      CTX[gb + (size_t)(i0 + r) * D_ + d] = 0.f;
    }
    return;
  }

  // stage Qu (32 rows) and Qv (33 rows) as bf16
  for (int idx = tid; idx < 33 * 64; idx += 256) {
    const int r = idx >> 6, d = idx & 63;
    const int gi = i0 + r;
    const float q = (gi < S_) ? Qf[gb + (size_t)gi * D_ + d] : 0.f;
    if (r < 32) Qus[r * 72 + d] = f2bf(q + ubias[h * DH_ + d]);
    Qvs[r * 72 + d] = f2bf(q + vbias[h * DH_ + d]);
  }
  if (tid < 32) { mrow[tid] = -3.0e38f; lrow[tid] = 0.f; arow[tid] = 0.f; }

  f32x4 ctx0 = {0.f, 0.f, 0.f, 0.f}, ctx1 = {0.f, 0.f, 0.f, 0.f};

  for (int j0 = 0; j0 < L; j0 += 64) {
    __syncthreads();  // prev iteration consumers of Vts/Pb/sc done
    // --- stage K (row-major) and V (transposed), bf16 ---
    for (int idx = tid; idx < 64 * 64; idx += 256) {
      const int j = idx >> 6, d = idx & 63;
      const int gj = j0 + j;
      float kv = 0.f, vv = 0.f;
      if (gj < S_) {
        kv = Kf[gb + (size_t)gj * D_ + d];
        vv = Vf[gb + (size_t)gj * D_ + d];
      }
      Ks[j * 72 + d]  = f2bf(kv);
      Vts[d * 72 + j] = f2bf(vv);
    }
    // --- stage P windows (96 rows each) ---
    const int A1 = L - 32 - i0 + j0;
    const int A2 = j0 - i0 - 33;
    for (int idx = tid; idx < 96 * 64; idx += 256) {
      const int p = idx >> 6, d = idx & 63;
      const int r1 = A1 + p, r2 = A2 + p;
      P1s[p * 72 + d] = f2bf((r1 >= 0 && r1 < S_) ? Pf[gb + (size_t)r1 * D_ + d] : 0.f);
      P2s[p * 72 + d] = f2bf((r2 >= 0 && r2 < S_) ? Pf[gb + (size_t)r2 * D_ + d] : 0.f);
    }
    __syncthreads();

    const int cthr = 31 + i0 - j0;
    const int jrem = L - j0;
    const int jmax = (jrem < 64) ? jrem : 64;

    // ---- MFMA phase: content (2 jobs/wave) + G1/G2 (6 jobs/wave) ----
    f32x4 cacc[2], gacc[6];
    bool guse[6];
#pragma unroll
    for (int t = 0; t < 2; ++t) {
      const int id = wave + 4 * t;
      const int Mt = id & 1, Nt = id >> 1;
      f32x4 acc = {0.f, 0.f, 0.f, 0.f};
      if (16 * Nt < jmax) {
        const ushort* ap = Qus + (16 * Mt + m16) * 72;
        const ushort* bp = Ks + (16 * Nt + m16) * 72;
#pragma unroll
        for (int ks = 0; ks < 2; ++ks)
          acc = __builtin_amdgcn_mfma_f32_16x16x32_bf16(
              *(const short8*)(ap + ks * 32 + koff0),
              *(const short8*)(bp + ks * 32 + koff0), acc, 0, 0, 0);
      }
      cacc[t] = acc;
    }
#pragma unroll
    for (int t = 0; t < 6; ++t) {
      const int id = wave + 4 * t;
      const bool isG2 = id >= 12;
      const int id2 = isG2 ? id - 12 : id;
      const int Mt = id2 & 1, Nt = id2 >> 1;
      const int ms = Mt + Nt;
      bool use = (ms >= 1) && (ms <= 5);           // jl-range overlap
      use = use && (isG2 ? (16 * Nt + 15 > cthr) : (16 * Nt <= cthr));
      guse[t] = use;
      f32x4 acc = {0.f, 0.f, 0.f, 0.f};
      if (use) {
        const ushort* ap = Qvs + ((isG2 ? 1 : 0) + 16 * Mt + m16) * 72;
        const ushort* bp = (isG2 ? P2s : P1s) + (16 * Nt + m16) * 72;
#pragma unroll
        for (int ks = 0; ks < 2; ++ks)
          acc = __builtin_amdgcn_mfma_f32_16x16x32_bf16(
              *(const short8*)(ap + ks * 32 + koff0),
              *(const short8*)(bp + ks * 32 + koff0), acc, 0, 0, 0);
      }
      gacc[t] = acc;
    }
    __syncthreads();  // MFMAs done -> P1s/P2s dead, sc region writable

    // ---- content C-frags -> sc ----
#pragma unroll
    for (int t = 0; t < 2; ++t) {
      const int id = wave + 4 * t;
      const int Mt = id & 1, Nt = id >> 1;
#pragma unroll
      for (int reg = 0; reg < 4; ++reg)
        sc[(16 * Mt + quad * 4 + reg) * 68 + 16 * Nt + m16] = cacc[t][reg];
    }
    __syncthreads();

    // ---- G scatter: sc[il][jl] += G[il][c], jl = c - 31 + il ----
#pragma unroll
    for (int t = 0; t < 6; ++t) {
      if (!guse[t]) continue;
      const int id = wave + 4 * t;
      const bool isG2 = id >= 12;
      const int id2 = isG2 ? id - 12 : id;
      const int Mt = id2 & 1, Nt = id2 >> 1;
      const int c = 16 * Nt + m16;
      const bool sel = isG2 ? (c > cthr) : (c <= cthr);
      if (sel) {
#pragma unroll
        for (int reg = 0; reg < 4; ++reg) {
          const int il = 16 * Mt + quad * 4 + reg;
          const int jl = c - 31 + il;
          if (jl >= 0 && jl < 64) sc[il * 68 + jl] += gacc[t][reg];
        }
      }
    }
    __syncthreads();

    // ---- softmax pass A: row max (8 threads/row) ----
    {
      const int row = tid >> 3, t8 = tid & 7, jb = t8 * 8;
      const float* sr = sc + row * 68 + jb;
      float mx = -3.0e38f;
#pragma unroll
      for (int q = 0; q < 8; ++q)
        if (jb + q < jmax) mx = fmaxf(mx, sr[q]);
#pragma unroll
      for (int off = 1; off < 8; off <<= 1)
        mx = fmaxf(mx, __shfl_xor(mx, off, 64));
      if (t8 == 0) {
        const float mo = mrow[row];
        const float mn = fmaxf(mo, mx);
        arow[row] = __expf((mo - mn) * OOS);
        mrow[row] = mn;
      }
    }
    __syncthreads();
    // ---- pass B: exp -> Pb (bf16), row sums ----
    {
      const int row = tid >> 3, t8 = tid & 7, jb = t8 * 8;
      const float m = mrow[row];
      const float* sr = sc + row * 68 + jb;
      float e[8], s = 0.f;
#pragma unroll
      for (int q = 0; q < 8; ++q) {
        float v = 0.f;
        if (jb + q < jmax) v = __expf((sr[q] - m) * OOS);
        e[q] = v;
        s += v;
      }
      ushort4 u0, u1;
      u0.x = f2bf(e[0]); u0.y = f2bf(e[1]); u0.z = f2bf(e[2]); u0.w = f2bf(e[3]);
      u1.x = f2bf(e[4]); u1.y = f2bf(e[5]); u1.z = f2bf(e[6]); u1.w = f2bf(e[7]);
      *(ushort4*)&Pb[row * 72 + jb] = u0;
      *(ushort4*)&Pb[row * 72 + jb + 4] = u1;
#pragma unroll
      for (int off = 1; off < 8; off <<= 1) s += __shfl_xor(s, off, 64);
      if (t8 == 0) lrow[row] = lrow[row] * arow[row] + s;
    }
    __syncthreads();

    // ---- PV: rescale + MFMA (wave owns rows 16*mw.., cols nw*32..+31) ----
    {
      float al[4];
#pragma unroll
      for (int reg = 0; reg < 4; ++reg) al[reg] = arow[16 * mw + quad * 4 + reg];
#pragma unroll
      for (int reg = 0; reg < 4; ++reg) { ctx0[reg] *= al[reg]; ctx1[reg] *= al[reg]; }
      const ushort* ap  = Pb + (16 * mw + m16) * 72;
      const ushort* b0p = Vts + (nw * 32 + m16) * 72;
      const ushort* b1p = Vts + (nw * 32 + 16 + m16) * 72;
#pragma unroll
      for (int ks = 0; ks < 2; ++ks) {
        const short8 a = *(const short8*)(ap + ks * 32 + koff0);
        ctx0 = __builtin_amdgcn_mfma_f32_16x16x32_bf16(
            a, *(const short8*)(b0p + ks * 32 + koff0), ctx0, 0, 0, 0);
        ctx1 = __builtin_amdgcn_mfma_f32_16x16x32_bf16(
            a, *(const short8*)(b1p + ks * 32 + koff0), ctx1, 0, 0, 0);
      }
    }
  }

  // ---- epilogue: normalize, zero masked rows ----
#pragma unroll
  for (int reg = 0; reg < 4; ++reg) {
    const int il = 16 * mw + quad * 4 + reg;
    const int gi = i0 + il;
    const float inv = (gi < L) ? (1.f / lrow[il]) : 0.f;
    CTX[gb + (size_t)gi * D_ + nw * 32 + m16]      = ctx0[reg] * inv;
    CTX[gb + (size_t)gi * D_ + nw * 32 + 16 + m16] = ctx1[reg] * inv;
  }
}

// ---------------------------------------------------------------------------
extern "C" void kernel_launch(void* const* d_in, const int* in_sizes, int n_in,
                              void* d_out, int out_size, void* d_ws, size_t ws_size,
                              hipStream_t stream)
{
  (void)in_sizes; (void)n_in; (void)out_size;
  const float* query = (const float*)d_in[0];
  const float* key   = (const float*)d_in[1];
  const float* value = (const float*)d_in[2];
  const float* pos   = (const float*)d_in[3];
  const float* Wq    = (const float*)d_in[4];
  const float* bq    = (const float*)d_in[5];
  const float* Wk    = (const float*)d_in[6];
  const float* bk    = (const float*)d_in[7];
  const float* Wv    = (const float*)d_in[8];
  const float* bv    = (const float*)d_in[9];
  const float* Wpos  = (const float*)d_in[10];
  const float* ub    = (const float*)d_in[11];
  const float* vb    = (const float*)d_in[12];
  const float* Wout  = (const float*)d_in[13];
  const float* bout  = (const float*)d_in[14];
  const int*   mask  = (const int*)d_in[15];

  const size_t TENS = (size_t)B_ * S_ * D_;
  float* ws = (float*)d_ws;
  float* Q   = ws + 0 * TENS;
  float* Kp  = ws + 1 * TENS;
  float* V   = ws + 2 * TENS;
  float* P   = ws + 3 * TENS;
  float* CTX = ws + 4 * TENS;
  int*   len = (int*)(ws + 5 * TENS);
  if (ws_size < (5 * TENS + 16) * sizeof(float)) return;

  const int M = B_ * S_;

  len_kernel<<<dim3(B_), dim3(256), 0, stream>>>(mask, len);

  dim3 gblk(256);
  dim3 ggrid(D_ / BN, M / BM);
  gemm_nt_bias<<<ggrid, gblk, 0, stream>>>(query, Wq, bq, Q, M, D_, D_);
  gemm_nt_bias<<<ggrid, gblk, 0, stream>>>(key,   Wk, bk, Kp, M, D_, D_);
  gemm_nt_bias<<<ggrid, gblk, 0, stream>>>(value, Wv, bv, V, M, D_, D_);
  gemm_nt_bias<<<ggrid, gblk, 0, stream>>>(pos,   Wpos, nullptr, P, M, D_, D_);

  attn_mfma<<<dim3(S_ / 32, H_, B_), dim3(256), 0, stream>>>(
      Q, Kp, V, P, ub, vb, len, CTX);

  gemm_nt_bias<<<ggrid, gblk, 0, stream>>>(CTX, Wout, bout, (float*)d_out, M, D_, D_);
}

// Round 4
// 1154.768 us; speedup vs baseline: 2.8023x; 1.4428x over previous
//
#include <hip/hip_runtime.h>

#define B_ 4
#define S_ 1024
#define D_ 1024
#define H_ 16
#define DH_ 64
#define OOS 0.03125f   // 1/sqrt(1024)

// plane sizes (ushort elements)
#define QPL (1088 * 64)       // Qu/Qv: 1024 rows + 64 pad rows (garbage-ok)
#define KPL (1024 * 64)       // K swizzled
#define VPL (1024 * 64)       // V^T swizzled
#define PPL (200 * 1024)      // P swizzled: 200 16-row blocks (rows -1056..2143)
#define PADLO 1056            // P row offset (multiple of 16)

typedef __attribute__((ext_vector_type(8))) short short8;
typedef __attribute__((ext_vector_type(4))) float f32x4;
typedef const __attribute__((address_space(1))) unsigned int* gas_t;
typedef __attribute__((address_space(3))) unsigned int* las_t;

__device__ __forceinline__ ushort f2bf(float x) {
  unsigned u = __float_as_uint(x);
  unsigned r = u + 0x7fffu + ((u >> 16) & 1u);
  return (ushort)(r >> 16);
}

union pack8 { ushort u[8]; uint4 v; };

// ---------------------------------------------------------------------------
// GEMM: C = A @ W^T (+bias). fp32 math. MODE selects epilogue:
// 0: fp32 C + bias (out-proj)
// 1: Q -> Qu_bf/Qv_bf planes [ph][s][d] bf16 (q+bq+u, q+bq+v)
// 2: K -> K_sw  frag-swizzled bf16
// 3: V -> Vt_sw frag-swizzled bf16 (transposed: n-dim=d, k-dim=j)
// 4: P -> P_sw  frag-swizzled bf16 at row offset PADLO, no bias
// ---------------------------------------------------------------------------
#define BM 128
#define BN 128
#define BK 16
#define TM 8
#define TN 8

template <int MODE>
__global__ __launch_bounds__(256) void gemm_nt(
    const float* __restrict__ A, const float* __restrict__ W,
    const float* __restrict__ bias, float* __restrict__ C,
    ushort* __restrict__ O1, ushort* __restrict__ O2,
    const float* __restrict__ ub, const float* __restrict__ vb,
    int M, int N, int K)
{
  __shared__ __align__(16) float As[BK][BM + 4];
  __shared__ __align__(16) float Ws[BK][BN + 4];
  const int tid = threadIdx.x;
  const int tx = tid & 15;
  const int ty = tid >> 4;
  const int m0 = blockIdx.y * BM;
  const int n0 = blockIdx.x * BN;

  float acc[TM][TN];
#pragma unroll
  for (int i = 0; i < TM; ++i)
#pragma unroll
    for (int j = 0; j < TN; ++j) acc[i][j] = 0.f;

  for (int k0 = 0; k0 < K; k0 += BK) {
#pragma unroll
    for (int r = 0; r < 2; ++r) {
      const int f = tid + 256 * r;
      const int row = f >> 2;
      const int c4 = (f & 3) << 2;
      float4 av = *(const float4*)(A + (size_t)(m0 + row) * K + k0 + c4);
      As[c4 + 0][row] = av.x;
      As[c4 + 1][row] = av.y;
      As[c4 + 2][row] = av.z;
      As[c4 + 3][row] = av.w;
      float4 wv = *(const float4*)(W + (size_t)(n0 + row) * K + k0 + c4);
      Ws[c4 + 0][row] = wv.x;
      Ws[c4 + 1][row] = wv.y;
      Ws[c4 + 2][row] = wv.z;
      Ws[c4 + 3][row] = wv.w;
    }
    __syncthreads();
#pragma unroll
    for (int kk = 0; kk < BK; ++kk) {
      float a[TM], w[TN];
      *(float4*)&a[0] = *(const float4*)&As[kk][ty * TM];
      *(float4*)&a[4] = *(const float4*)&As[kk][ty * TM + 4];
      *(float4*)&w[0] = *(const float4*)&Ws[kk][tx * TN];
      *(float4*)&w[4] = *(const float4*)&Ws[kk][tx * TN + 4];
#pragma unroll
      for (int i = 0; i < TM; ++i)
#pragma unroll
        for (int j = 0; j < TN; ++j) acc[i][j] = fmaf(a[i], w[j], acc[i][j]);
    }
    __syncthreads();
  }

  if (MODE == 0) {
#pragma unroll
    for (int i = 0; i < TM; ++i) {
      float* cp = C + (size_t)(m0 + ty * TM + i) * N + n0 + tx * TN;
#pragma unroll
      for (int j = 0; j < TN; j += 4) {
        float4 v;
        v.x = acc[i][j + 0] + bias[n0 + tx * TN + j + 0];
        v.y = acc[i][j + 1] + bias[n0 + tx * TN + j + 1];
        v.z = acc[i][j + 2] + bias[n0 + tx * TN + j + 2];
        v.w = acc[i][j + 3] + bias[n0 + tx * TN + j + 3];
        *(float4*)(cp + j) = v;
      }
    }
  } else if (MODE == 1) {
    const int n = n0 + tx * TN;
    const int h = n >> 6, d = n & 63;
#pragma unroll
    for (int i = 0; i < TM; ++i) {
      const int s = m0 + ty * TM + i;
      const int bb = s >> 10, sr = s & 1023;
      const size_t base = (size_t)(bb * 16 + h) * QPL + (size_t)sr * 64 + d;
      pack8 pu, pv;
#pragma unroll
      for (int j = 0; j < TN; ++j) {
        const float q = acc[i][j] + bias[n + j];
        pu.u[j] = f2bf(q + ub[n + j]);
        pv.u[j] = f2bf(q + vb[n + j]);
      }
      *(uint4*)(O1 + base) = pu.v;
      *(uint4*)(O2 + base) = pv.v;
    }
  } else if (MODE == 2 || MODE == 4) {
    const int n = n0 + tx * TN;
    const int h = n >> 6, dd = n & 63;
    const int ks = dd >> 5, qk = (dd >> 3) & 3;
#pragma unroll
    for (int i = 0; i < TM; ++i) {
      const int tok = m0 + ty * TM + i;
      const int bb = tok >> 10, jr = tok & 1023;
      size_t base;
      if (MODE == 2)
        base = (size_t)(bb * 16 + h) * KPL + (size_t)(jr >> 6) * 4096 +
               (size_t)((((jr >> 4) & 3) * 2 + ks)) * 512 + (qk * 16 + (jr & 15)) * 8;
      else {
        const int ro = jr + PADLO;
        base = (size_t)(bb * 16 + h) * PPL + (size_t)(ro >> 4) * 1024 +
               (size_t)ks * 512 + (qk * 16 + (ro & 15)) * 8;
      }
      pack8 p;
#pragma unroll
      for (int j = 0; j < TN; ++j)
        p.u[j] = f2bf(acc[i][j] + (MODE == 2 ? bias[n + j] : 0.f));
      *(uint4*)(O1 + base) = p.v;
    }
  } else {  // MODE 3: V transposed
    const int m = m0 + ty * TM;
    const int bb = m >> 10, jr = m & 1023;
    const int jt = jr >> 6, ksj = (jr >> 5) & 1, qk = (jr >> 3) & 3;
#pragma unroll
    for (int jc = 0; jc < TN; ++jc) {
      const int n = n0 + tx * TN + jc;
      const int h = n >> 6, dd = n & 63;
      const int subd = dd >> 4, nn = dd & 15;
      const size_t base = (size_t)(bb * 16 + h) * VPL + (size_t)jt * 4096 +
                          (size_t)(subd * 2 + ksj) * 512 + (qk * 16 + nn) * 8;
      const float bv_ = bias[n];
      pack8 p;
#pragma unroll
      for (int i = 0; i < TM; ++i) p.u[i] = f2bf(acc[i][jc] + bv_);
      *(uint4*)(O1 + base) = p.v;
    }
  }
}

// ---------------------------------------------------------------------------
// len + zero P_sw row r=-1 (ro=1055: block 65, rr=15) per plane of this batch
// ---------------------------------------------------------------------------
__global__ void len_kernel(const int* __restrict__ mask, int* __restrict__ len,
                           ushort* __restrict__ Psw)
{
  const int b = blockIdx.x;
  int cnt = 0;
  for (int i = threadIdx.x; i < S_; i += 256)
    cnt += (mask[(size_t)b * S_ * S_ + (size_t)i * S_] != 0) ? 1 : 0;
  __shared__ int sh[256];
  sh[threadIdx.x] = cnt;
  __syncthreads();
  for (int off = 128; off > 0; off >>= 1) {
    if (threadIdx.x < off) sh[threadIdx.x] += sh[threadIdx.x + off];
    __syncthreads();
  }
  if (threadIdx.x == 0) len[b] = S_ - sh[0];
  for (int idx = threadIdx.x; idx < 16 * 64; idx += 256) {
    const int h = idx >> 6, d = idx & 63;
    Psw[(size_t)(b * 16 + h) * PPL + 65 * 1024 + (d >> 5) * 512 +
        (((d >> 3) & 3) * 16 + 15) * 8 + (d & 7)] = 0;
  }
}

// ---------------------------------------------------------------------------
// MFMA flash attention, DMA-staged. Block = (i-tile of 32, h, b), 4 waves.
// LDS: Ks[4096] | Vts[4096] | PW[14336] (P1|P2, unioned with sc+Pb after MFMA)
// ---------------------------------------------------------------------------
__global__ __launch_bounds__(256, 3) void attn_mfma2(
    const ushort* __restrict__ Qu, const ushort* __restrict__ Qv,
    const ushort* __restrict__ Ksw, const ushort* __restrict__ Vsw,
    const ushort* __restrict__ Psw, const int* __restrict__ len,
    float* __restrict__ CTX)
{
  __shared__ __align__(16) ushort SMEM[22528];
  __shared__ float mrow[32], lrow[32], arow[32];

  ushort* const Ks_  = SMEM;             // 4096
  ushort* const Vts_ = SMEM + 4096;      // 4096
  ushort* const P1s_ = SMEM + 8192;      // 7168
  ushort* const P2s_ = SMEM + 15360;     // 7168
  float*  const sc   = (float*)(SMEM + 8192);          // 32x68 fp32 (8704 B)
  ushort* const Pb   = SMEM + 8192 + 4352;             // 32x72 bf16 (4608 B)

  const int tid  = threadIdx.x;
  const int wave = tid >> 6, lane = tid & 63;
  const int m16  = lane & 15, quad = lane >> 4;
  const int mw   = wave & 1,  nw   = wave >> 1;
  const int koff0 = quad * 8;

  const int i0 = blockIdx.x * 32;
  const int h  = blockIdx.y;
  const int b  = blockIdx.z;
  const int ph = b * 16 + h;
  const int L  = len[b];
  const size_t gb = ((size_t)b * S_) * D_ + h * DH_;

  if (i0 >= L) {
    for (int idx = tid; idx < 32 * 64; idx += 256) {
      const int r = idx >> 6, d = idx & 63;
      CTX[gb + (size_t)(i0 + r) * D_ + d] = 0.f;
    }
    return;
  }

  // ---- preload Q fragments to registers (reused across all j-tiles) ----
  const ushort* quP = Qu + (size_t)ph * QPL;
  const ushort* qvP = Qv + (size_t)ph * QPL;
  short8 qufr[2][2], qvfr[2][2][2];  // [Mt][ks], [off][Mt][ks]
#pragma unroll
  for (int Mt = 0; Mt < 2; ++Mt)
#pragma unroll
    for (int ks = 0; ks < 2; ++ks) {
      qufr[Mt][ks] = *(const short8*)(quP + (size_t)(i0 + 16 * Mt + m16) * 64 + ks * 32 + koff0);
#pragma unroll
      for (int off = 0; off < 2; ++off)
        qvfr[off][Mt][ks] =
            *(const short8*)(qvP + (size_t)(i0 + off + 16 * Mt + m16) * 64 + ks * 32 + koff0);
    }

  if (tid < 32) { mrow[tid] = -3.0e38f; lrow[tid] = 0.f; arow[tid] = 0.f; }

  f32x4 ctx0 = {0.f, 0.f, 0.f, 0.f}, ctx1 = {0.f, 0.f, 0.f, 0.f};

  const ushort* ksP = Ksw + (size_t)ph * KPL;
  const ushort* vsP = Vsw + (size_t)ph * VPL;
  const ushort* psP = Psw + (size_t)ph * PPL;

  for (int j0 = 0; j0 < L; j0 += 64) {
    __syncthreads();  // prior-tile consumers done before DMA overwrites LDS

    const int jt = j0 >> 6;
    const int A1 = L - 32 - i0 + j0, A2 = j0 - i0 - 33;
    const int ro1 = A1 + PADLO, ro2 = A2 + PADLO;
    const int rb1 = ro1 >> 4, rb2 = ro2 >> 4;
    const int d1 = ro1 & 15, d2 = ro2 & 15;

    // ---- 44 async DMA insts: 8 K + 8 V + 14 P1 + 14 P2 (1 KB each) ----
    {
      const ushort* kgo = ksP + (size_t)jt * 4096;
      const ushort* vgo = vsP + (size_t)jt * 4096;
      const ushort* p1o = psP + (size_t)rb1 * 1024;
      const ushort* p2o = psP + (size_t)rb2 * 1024;
      for (int t = wave; t < 44; t += 4) {
        const ushort* g;
        int l;
        if (t < 8)       { g = kgo + t * 512;        l = t * 512; }
        else if (t < 16) { g = vgo + (t - 8) * 512;  l = 4096 + (t - 8) * 512; }
        else if (t < 30) { g = p1o + (t - 16) * 512; l = 8192 + (t - 16) * 512; }
        else             { g = p2o + (t - 30) * 512; l = 15360 + (t - 30) * 512; }
        __builtin_amdgcn_global_load_lds((gas_t)(g + lane * 8), (las_t)(SMEM + l), 16, 0, 0);
      }
    }
    __syncthreads();  // all DMA landed

    const int jrem = L - j0;
    const int jmax = (jrem < 64) ? jrem : 64;
    const int cthr = 31 + i0 - j0;

    // ---- MFMA phase: 36 jobs (8 content, 14 G1, 14 G2), 9 per wave ----
    f32x4 av[9];
#pragma unroll
    for (int t = 0; t < 9; ++t) {
      const int id = wave + 4 * t;
      f32x4 a = {0.f, 0.f, 0.f, 0.f};
      if (id < 8) {
        const int Mt = id & 1, Nt = id >> 1;
        if (16 * Nt < jmax) {
          const ushort* bp = Ks_ + (Nt * 2) * 512 + lane * 8;
          a = __builtin_amdgcn_mfma_f32_16x16x32_bf16(qufr[Mt][0], *(const short8*)bp, a, 0, 0, 0);
          a = __builtin_amdgcn_mfma_f32_16x16x32_bf16(qufr[Mt][1], *(const short8*)(bp + 512), a, 0, 0, 0);
        }
      } else if (id < 22) {
        const int e = id - 8, Mt = e & 1, Ntp = e >> 1;
        const int sm = 16 * (Ntp + Mt);
        if (sm >= d1 + 1 && sm <= jmax + d1 + 30 && 16 * Ntp - d1 <= cthr) {
          const ushort* bp = P1s_ + (Ntp * 2) * 512 + lane * 8;
          a = __builtin_amdgcn_mfma_f32_16x16x32_bf16(qvfr[0][Mt][0], *(const short8*)bp, a, 0, 0, 0);
          a = __builtin_amdgcn_mfma_f32_16x16x32_bf16(qvfr[0][Mt][1], *(const short8*)(bp + 512), a, 0, 0, 0);
        }
      } else {
        const int e = id - 22, Mt = e & 1, Ntp = e >> 1;
        const int sm = 16 * (Ntp + Mt);
        if (sm >= d2 + 1 && sm <= jmax + d2 + 30 && 16 * Ntp + 15 - d2 > cthr) {
          const ushort* bp = P2s_ + (Ntp * 2) * 512 + lane * 8;
          a = __builtin_amdgcn_mfma_f32_16x16x32_bf16(qvfr[1][Mt][0], *(const short8*)bp, a, 0, 0, 0);
          a = __builtin_amdgcn_mfma_f32_16x16x32_bf16(qvfr[1][Mt][1], *(const short8*)(bp + 512), a, 0, 0, 0);
        }
      }
      av[t] = a;
    }
    __syncthreads();  // P windows dead -> sc region writable

    // ---- content C-frags -> sc ----
#pragma unroll
    for (int t = 0; t < 9; ++t) {
      const int id = wave + 4 * t;
      if (id < 8) {
        const int Mt = id & 1, Nt = id >> 1;
        if (16 * Nt < jmax) {
#pragma unroll
          for (int reg = 0; reg < 4; ++reg)
            sc[(16 * Mt + quad * 4 + reg) * 68 + 16 * Nt + m16] = av[t][reg];
        }
      }
    }
    __syncthreads();

    // ---- G scatter: sc[il][jl] += G[il][c], jl = c-31+il, c = c_win - delta ----
#pragma unroll
    for (int t = 0; t < 9; ++t) {
      const int id = wave + 4 * t;
      if (id >= 8) {
        const bool isG2 = id >= 22;
        const int e = id - (isG2 ? 22 : 8), Mt = e & 1, Ntp = e >> 1;
        const int dl = isG2 ? d2 : d1;
        const int sm = 16 * (Ntp + Mt);
        const bool use = sm >= dl + 1 && sm <= jmax + dl + 30 &&
                         (isG2 ? (16 * Ntp + 15 - dl > cthr) : (16 * Ntp - dl <= cthr));
        if (use) {
          const int c = 16 * Ntp + m16 - dl;
          const bool sel = isG2 ? (c > cthr) : (c <= cthr);
          if (sel) {
#pragma unroll
            for (int reg = 0; reg < 4; ++reg) {
              const int il = 16 * Mt + quad * 4 + reg;
              const int jl = c - 31 + il;
              if (jl >= 0 && jl < 64) sc[il * 68 + jl] += av[t][reg];
            }
          }
        }
      }
    }
    __syncthreads();

    // ---- softmax pass A: row max (8 threads/row) ----
    {
      const int row = tid >> 3, t8 = tid & 7, jb = t8 * 8;
      const float* sr = sc + row * 68 + jb;
      float mx = -3.0e38f;
#pragma unroll
      for (int q = 0; q < 8; ++q)
        if (jb + q < jmax) mx = fmaxf(mx, sr[q]);
#pragma unroll
      for (int off = 1; off < 8; off <<= 1)
        mx = fmaxf(mx, __shfl_xor(mx, off, 64));
      if (t8 == 0) {
        const float mo = mrow[row];
        const float mn = fmaxf(mo, mx);
        arow[row] = __expf((mo - mn) * OOS);
        mrow[row] = mn;
      }
    }
    __syncthreads();
    // ---- pass B: exp -> Pb (bf16), row sums ----
    {
      const int row = tid >> 3, t8 = tid & 7, jb = t8 * 8;
      const float m = mrow[row];
      const float* sr = sc + row * 68 + jb;
      float e[8], s = 0.f;
#pragma unroll
      for (int q = 0; q < 8; ++q) {
        float v = 0.f;
        if (jb + q < jmax) v = __expf((sr[q] - m) * OOS);
        e[q] = v;
        s += v;
      }
      ushort4 u0, u1;
      u0.x = f2bf(e[0]); u0.y = f2bf(e[1]); u0.z = f2bf(e[2]); u0.w = f2bf(e[3]);
      u1.x = f2bf(e[4]); u1.y = f2bf(e[5]); u1.z = f2bf(e[6]); u1.w = f2bf(e[7]);
      *(ushort4*)&Pb[row * 72 + jb] = u0;
      *(ushort4*)&Pb[row * 72 + jb + 4] = u1;
#pragma unroll
      for (int off = 1; off < 8; off <<= 1) s += __shfl_xor(s, off, 64);
      if (t8 == 0) lrow[row] = lrow[row] * arow[row] + s;
    }
    __syncthreads();

    // ---- PV: rescale + MFMA ----
    {
      float al[4];
#pragma unroll
      for (int reg = 0; reg < 4; ++reg) al[reg] = arow[16 * mw + quad * 4 + reg];
#pragma unroll
      for (int reg = 0; reg < 4; ++reg) { ctx0[reg] *= al[reg]; ctx1[reg] *= al[reg]; }
      const ushort* ap = Pb + (16 * mw + m16) * 72;
#pragma unroll
      for (int ksj = 0; ksj < 2; ++ksj) {
        const short8 a = *(const short8*)(ap + ksj * 32 + koff0);
        ctx0 = __builtin_amdgcn_mfma_f32_16x16x32_bf16(
            a, *(const short8*)(Vts_ + ((nw * 2) * 2 + ksj) * 512 + lane * 8), ctx0, 0, 0, 0);
        ctx1 = __builtin_amdgcn_mfma_f32_16x16x32_bf16(
            a, *(const short8*)(Vts_ + ((nw * 2 + 1) * 2 + ksj) * 512 + lane * 8), ctx1, 0, 0, 0);
      }
    }
  }

  // ---- epilogue ----
#pragma unroll
  for (int reg = 0; reg < 4; ++reg) {
    const int il = 16 * mw + quad * 4 + reg;
    const int gi = i0 + il;
    const float inv = (gi < L) ? (1.f / lrow[il]) : 0.f;
    CTX[gb + (size_t)gi * D_ + nw * 32 + m16]      = ctx0[reg] * inv;
    CTX[gb + (size_t)gi * D_ + nw * 32 + 16 + m16] = ctx1[reg] * inv;
  }
}

// ---------------------------------------------------------------------------
extern "C" void kernel_launch(void* const* d_in, const int* in_sizes, int n_in,
                              void* d_out, int out_size, void* d_ws, size_t ws_size,
                              hipStream_t stream)
{
  (void)in_sizes; (void)n_in; (void)out_size;
  const float* query = (const float*)d_in[0];
  const float* key   = (const float*)d_in[1];
  const float* value = (const float*)d_in[2];
  const float* pos   = (const float*)d_in[3];
  const float* Wq    = (const float*)d_in[4];
  const float* bq    = (const float*)d_in[5];
  const float* Wk    = (const float*)d_in[6];
  const float* bk    = (const float*)d_in[7];
  const float* Wv    = (const float*)d_in[8];
  const float* bv    = (const float*)d_in[9];
  const float* Wpos  = (const float*)d_in[10];
  const float* ub    = (const float*)d_in[11];
  const float* vb    = (const float*)d_in[12];
  const float* Wout  = (const float*)d_in[13];
  const float* bout  = (const float*)d_in[14];
  const int*   mask  = (const int*)d_in[15];

  float*  CTX = (float*)d_ws;
  ushort* Qu  = (ushort*)((char*)d_ws + 16777216);
  ushort* Qv  = Qu + (size_t)64 * QPL;
  ushort* Ksw = Qv + (size_t)64 * QPL;
  ushort* Vsw = Ksw + (size_t)64 * KPL;
  ushort* Psw = Vsw + (size_t)64 * VPL;
  int*    len = (int*)(Psw + (size_t)64 * PPL);
  const size_t need = 16777216 + 2 * (size_t)64 * QPL * 2 + 2 * (size_t)64 * KPL * 2 +
                      (size_t)64 * PPL * 2 + 256;
  if (ws_size < need) return;

  const int M = B_ * S_;

  len_kernel<<<dim3(B_), dim3(256), 0, stream>>>(mask, len, Psw);

  dim3 gblk(256);
  dim3 ggrid(D_ / BN, M / BM);
  gemm_nt<1><<<ggrid, gblk, 0, stream>>>(query, Wq, bq, nullptr, Qu, Qv, ub, vb, M, D_, D_);
  gemm_nt<2><<<ggrid, gblk, 0, stream>>>(key,   Wk, bk, nullptr, Ksw, nullptr, nullptr, nullptr, M, D_, D_);
  gemm_nt<3><<<ggrid, gblk, 0, stream>>>(value, Wv, bv, nullptr, Vsw, nullptr, nullptr, nullptr, M, D_, D_);
  gemm_nt<4><<<ggrid, gblk, 0, stream>>>(pos,   Wpos, nullptr, nullptr, Psw, nullptr, nullptr, nullptr, M, D_, D_);

  attn_mfma2<<<dim3(S_ / 32, H_, B_), dim3(256), 0, stream>>>(
      Qu, Qv, Ksw, Vsw, Psw, len, CTX);

  gemm_nt<0><<<ggrid, gblk, 0, stream>>>(CTX, Wout, bout, (float*)d_out, nullptr, nullptr,
                                         nullptr, nullptr, M, D_, D_);
}

// Round 5
// 730.597 us; speedup vs baseline: 4.4293x; 1.5806x over previous
//
#include <hip/hip_runtime.h>

#define B_ 4
#define S_ 1024
#define D_ 1024
#define H_ 16
#define DH_ 64
#define OOS 0.03125f   // 1/sqrt(1024)

// attn-consumable plane sizes (ushort elements)
#define QPL (1088 * 64)       // Qu/Qv: 1024 rows + 64 pad rows (garbage-ok)
#define KPL (1024 * 64)       // K swizzled
#define VPL (1024 * 64)       // V^T swizzled
#define PPL (200 * 1024)      // P swizzled: rows -1056..2143
#define PADLO 1056

// GEMM-operand swizzled planes: blocks of 16 rows x 32 k = 512 ushorts
#define APL_SW (256 * 32 * 512)   // 4096-row activations
#define WPL_SW (64 * 32 * 512)    // 1024-row weights

typedef __attribute__((ext_vector_type(8))) short short8;
typedef __attribute__((ext_vector_type(4))) float f32x4;
typedef const __attribute__((address_space(1))) unsigned int* gas_t;
typedef __attribute__((address_space(3))) unsigned int* las_t;

__device__ __forceinline__ ushort f2bf(float x) {
  unsigned u = __float_as_uint(x);
  unsigned r = u + 0x7fffu + ((u >> 16) & 1u);
  return (ushort)(r >> 16);
}
__device__ __forceinline__ float bf2f(ushort u) {
  return __uint_as_float(((unsigned)u) << 16);
}

union pack8 { ushort u[8]; uint4 v; };

// ---------------------------------------------------------------------------
// fp32 -> (hi, lo) bf16 split, written in GEMM-fragment-swizzled block layout.
// One block per 16-row t-tile; K = 1024 fixed.
// addr(t,k) = blk(tt, k>>5)*512 + ((k&31)>>3)*128 + (t&15)*8 + (k&7)
// ---------------------------------------------------------------------------
struct ConvDesc { const float* src; ushort* hi; ushort* lo; };
struct ConvArgs { ConvDesc d[5]; };

__global__ __launch_bounds__(256) void conv_split(ConvArgs args)
{
  const ConvDesc dd = args.d[blockIdx.y];
  const int tt = blockIdx.x;
  const int tid = threadIdx.x;
  const float* src = dd.src + (size_t)tt * 16 * 1024;
  ushort* hi = dd.hi + (size_t)tt * 32 * 512;
  ushort* lo = dd.lo + (size_t)tt * 32 * 512;
#pragma unroll 4
  for (int q = 0; q < 16; ++q) {
    const int s = q * 256 + tid;
    const int r = s >> 8, c4 = s & 255;
    const float4 x = *(const float4*)(src + r * 1024 + c4 * 4);
    const int k = c4 * 4;
    const size_t addr = (size_t)(k >> 5) * 512 + ((k & 31) >> 3) * 128 + r * 8 + (k & 7);
    ushort4 hu, lu;
    hu.x = f2bf(x.x); lu.x = f2bf(x.x - bf2f(hu.x));
    hu.y = f2bf(x.y); lu.y = f2bf(x.y - bf2f(hu.y));
    hu.z = f2bf(x.z); lu.z = f2bf(x.z - bf2f(hu.z));
    hu.w = f2bf(x.w); lu.w = f2bf(x.w - bf2f(hu.w));
    *(ushort4*)(hi + addr) = hu;
    *(ushort4*)(lo + addr) = lu;
  }
}

// ---------------------------------------------------------------------------
// bf16x3 MFMA GEMM: C[M,N] = A[M,K] @ W[N,K]^T (+bias), K=1024, N=1024.
// Tile 64(M) x 128(N), BK=32, 4 waves as 2x2 of 32x64. acc += ah*bh + ah*bl + al*bh.
// Epilogue MODE: 0 fp32+bias -> C; 1 -> Qu/Qv planes; 2 -> Ksw; 3 -> Vsw (transposed);
// 4 -> Psw (no bias).
// ---------------------------------------------------------------------------
template <int MODE>
__global__ __launch_bounds__(256, 2) void gemm_bf16x3(
    const ushort* __restrict__ Ahi, const ushort* __restrict__ Alo,
    const ushort* __restrict__ Bhi, const ushort* __restrict__ Blo,
    const float* __restrict__ bias, float* __restrict__ C,
    ushort* __restrict__ O1, ushort* __restrict__ O2,
    const float* __restrict__ ub, const float* __restrict__ vb)
{
  __shared__ __align__(16) ushort SM[12288];  // 24 KB staging; epilogue 16 KB union
  const int tid = threadIdx.x;
  const int wave = tid >> 6, lane = tid & 63;
  const int m16 = lane & 15, quad = lane >> 4;
  const int mw2 = wave & 1, nw2 = wave >> 1;
  const int mt0 = blockIdx.y * 4;   // A t-tile base (16-row units)
  const int nt0 = blockIdx.x * 8;   // B t-tile base

  f32x4 acc[2][4];
#pragma unroll
  for (int mf = 0; mf < 2; ++mf)
#pragma unroll
    for (int nf = 0; nf < 4; ++nf) acc[mf][nf] = (f32x4){0.f, 0.f, 0.f, 0.f};

  for (int kb = 0; kb < 32; ++kb) {
    __syncthreads();
    for (int t = wave; t < 24; t += 4) {
      const ushort* g;
      int l;
      if (t < 4)       { g = Ahi + ((size_t)(mt0 + t) * 32 + kb) * 512;      l = t * 512; }
      else if (t < 8)  { g = Alo + ((size_t)(mt0 + t - 4) * 32 + kb) * 512;  l = 2048 + (t - 4) * 512; }
      else if (t < 16) { g = Bhi + ((size_t)(nt0 + t - 8) * 32 + kb) * 512;  l = 4096 + (t - 8) * 512; }
      else             { g = Blo + ((size_t)(nt0 + t - 16) * 32 + kb) * 512; l = 8192 + (t - 16) * 512; }
      __builtin_amdgcn_global_load_lds((gas_t)(g + lane * 8), (las_t)(SM + l), 16, 0, 0);
    }
    __syncthreads();
    short8 ah[2], al[2], bh[4], bl[4];
#pragma unroll
    for (int mf = 0; mf < 2; ++mf) {
      ah[mf] = *(const short8*)(SM + (mw2 * 2 + mf) * 512 + lane * 8);
      al[mf] = *(const short8*)(SM + 2048 + (mw2 * 2 + mf) * 512 + lane * 8);
    }
#pragma unroll
    for (int nf = 0; nf < 4; ++nf) {
      bh[nf] = *(const short8*)(SM + 4096 + (nw2 * 4 + nf) * 512 + lane * 8);
      bl[nf] = *(const short8*)(SM + 8192 + (nw2 * 4 + nf) * 512 + lane * 8);
    }
#pragma unroll
    for (int mf = 0; mf < 2; ++mf)
#pragma unroll
      for (int nf = 0; nf < 4; ++nf) {
        acc[mf][nf] = __builtin_amdgcn_mfma_f32_16x16x32_bf16(ah[mf], bh[nf], acc[mf][nf], 0, 0, 0);
        acc[mf][nf] = __builtin_amdgcn_mfma_f32_16x16x32_bf16(ah[mf], bl[nf], acc[mf][nf], 0, 0, 0);
        acc[mf][nf] = __builtin_amdgcn_mfma_f32_16x16x32_bf16(al[mf], bh[nf], acc[mf][nf], 0, 0, 0);
      }
  }

  // ---- epilogue via LDS transpose: chunks of 64 n-cols ----
  const int Mb = blockIdx.y * 64, Nb = blockIdx.x * 128;
  float* const E = (float*)SM;  // [64][64]
#pragma unroll
  for (int c = 0; c < 2; ++c) {
    __syncthreads();
    if (nw2 == c) {
#pragma unroll
      for (int mf = 0; mf < 2; ++mf)
#pragma unroll
        for (int nf = 0; nf < 4; ++nf)
#pragma unroll
          for (int reg = 0; reg < 4; ++reg)
            E[(mw2 * 32 + mf * 16 + quad * 4 + reg) * 64 + nf * 16 + m16] = acc[mf][nf][reg];
    }
    __syncthreads();

    if (MODE == 3) {
#pragma unroll
      for (int q = 0; q < 2; ++q) {
        const int s = tid + 256 * q;
        const int cc = s & 63, rg = s >> 6;             // col, row-group of 8
        const int tok0 = Mb + rg * 8;
        const int n = Nb + c * 64 + cc;
        const int bb = tok0 >> 10, jr = tok0 & 1023;
        const int jt = jr >> 6, ksj = (jr >> 5) & 1, qk = (jr >> 3) & 3;
        const int h = n >> 6, dd = n & 63;
        const int subd = dd >> 4, nn = dd & 15;
        const size_t base = (size_t)(bb * 16 + h) * VPL + (size_t)jt * 4096 +
                            (size_t)(subd * 2 + ksj) * 512 + (qk * 16 + nn) * 8;
        const float bvv = bias[n];
        pack8 p;
#pragma unroll
        for (int i = 0; i < 8; ++i) p.u[i] = f2bf(E[(rg * 8 + i) * 64 + cc] + bvv);
        *(uint4*)(O1 + base) = p.v;
      }
    } else {
#pragma unroll
      for (int q = 0; q < 2; ++q) {
        const int s = tid + 256 * q;
        const int r = s >> 3, g = s & 7;
        const int token = Mb + r;
        const int n = Nb + c * 64 + g * 8;
        float v[8];
        *(float4*)&v[0] = *(const float4*)&E[r * 64 + g * 8];
        *(float4*)&v[4] = *(const float4*)&E[r * 64 + g * 8 + 4];
        if (MODE == 0) {
          float4 o0, o1;
          o0.x = v[0] + bias[n + 0]; o0.y = v[1] + bias[n + 1];
          o0.z = v[2] + bias[n + 2]; o0.w = v[3] + bias[n + 3];
          o1.x = v[4] + bias[n + 4]; o1.y = v[5] + bias[n + 5];
          o1.z = v[6] + bias[n + 6]; o1.w = v[7] + bias[n + 7];
          *(float4*)(C + (size_t)token * 1024 + n) = o0;
          *(float4*)(C + (size_t)token * 1024 + n + 4) = o1;
        } else if (MODE == 1) {
          const int bb = token >> 10, sr = token & 1023;
          const int h = n >> 6, d = n & 63;
          const size_t base = (size_t)(bb * 16 + h) * QPL + (size_t)sr * 64 + d;
          pack8 pu, pv;
#pragma unroll
          for (int j = 0; j < 8; ++j) {
            const float qv_ = v[j] + bias[n + j];
            pu.u[j] = f2bf(qv_ + ub[n + j]);
            pv.u[j] = f2bf(qv_ + vb[n + j]);
          }
          *(uint4*)(O1 + base) = pu.v;
          *(uint4*)(O2 + base) = pv.v;
        } else {  // MODE 2 (Ksw) or 4 (Psw)
          const int bb = token >> 10, jr = token & 1023;
          const int h = n >> 6, dd = n & 63;
          const int ks = dd >> 5, qk = (dd >> 3) & 3;
          size_t base;
          if (MODE == 2)
            base = (size_t)(bb * 16 + h) * KPL + (size_t)(jr >> 6) * 4096 +
                   (size_t)((((jr >> 4) & 3) * 2 + ks)) * 512 + (qk * 16 + (jr & 15)) * 8;
          else {
            const int ro = jr + PADLO;
            base = (size_t)(bb * 16 + h) * PPL + (size_t)(ro >> 4) * 1024 +
                   (size_t)ks * 512 + (qk * 16 + (ro & 15)) * 8;
          }
          pack8 p;
#pragma unroll
          for (int j = 0; j < 8; ++j)
            p.u[j] = f2bf(v[j] + (MODE == 2 ? bias[n + j] : 0.f));
          *(uint4*)(O1 + base) = p.v;
        }
      }
    }
  }
}

// ---------------------------------------------------------------------------
// len + zero P_sw row r=-1 (ro=1055: block 65, rr=15) per plane of this batch
// ---------------------------------------------------------------------------
__global__ void len_kernel(const int* __restrict__ mask, int* __restrict__ len,
                           ushort* __restrict__ Psw)
{
  const int b = blockIdx.x;
  int cnt = 0;
  for (int i = threadIdx.x; i < S_; i += 256)
    cnt += (mask[(size_t)b * S_ * S_ + (size_t)i * S_] != 0) ? 1 : 0;
  __shared__ int sh[256];
  sh[threadIdx.x] = cnt;
  __syncthreads();
  for (int off = 128; off > 0; off >>= 1) {
    if (threadIdx.x < off) sh[threadIdx.x] += sh[threadIdx.x + off];
    __syncthreads();
  }
  if (threadIdx.x == 0) len[b] = S_ - sh[0];
  for (int idx = threadIdx.x; idx < 16 * 64; idx += 256) {
    const int h = idx >> 6, d = idx & 63;
    Psw[(size_t)(b * 16 + h) * PPL + 65 * 1024 + (d >> 5) * 512 +
        (((d >> 3) & 3) * 16 + 15) * 8 + (d & 7)] = 0;
  }
}

// ---------------------------------------------------------------------------
// MFMA flash attention, DMA-staged (unchanged from round 4).
// ---------------------------------------------------------------------------
__global__ __launch_bounds__(256, 3) void attn_mfma2(
    const ushort* __restrict__ Qu, const ushort* __restrict__ Qv,
    const ushort* __restrict__ Ksw, const ushort* __restrict__ Vsw,
    const ushort* __restrict__ Psw, const int* __restrict__ len,
    float* __restrict__ CTX)
{
  __shared__ __align__(16) ushort SMEM[22528];
  __shared__ float mrow[32], lrow[32], arow[32];

  ushort* const Ks_  = SMEM;
  ushort* const Vts_ = SMEM + 4096;
  ushort* const P1s_ = SMEM + 8192;
  ushort* const P2s_ = SMEM + 15360;
  float*  const sc   = (float*)(SMEM + 8192);
  ushort* const Pb   = SMEM + 8192 + 4352;

  const int tid  = threadIdx.x;
  const int wave = tid >> 6, lane = tid & 63;
  const int m16  = lane & 15, quad = lane >> 4;
  const int mw   = wave & 1,  nw   = wave >> 1;
  const int koff0 = quad * 8;

  const int i0 = blockIdx.x * 32;
  const int h  = blockIdx.y;
  const int b  = blockIdx.z;
  const int ph = b * 16 + h;
  const int L  = len[b];
  const size_t gb = ((size_t)b * S_) * D_ + h * DH_;

  if (i0 >= L) {
    for (int idx = tid; idx < 32 * 64; idx += 256) {
      const int r = idx >> 6, d = idx & 63;
      CTX[gb + (size_t)(i0 + r) * D_ + d] = 0.f;
    }
    return;
  }

  const ushort* quP = Qu + (size_t)ph * QPL;
  const ushort* qvP = Qv + (size_t)ph * QPL;
  short8 qufr[2][2], qvfr[2][2][2];
#pragma unroll
  for (int Mt = 0; Mt < 2; ++Mt)
#pragma unroll
    for (int ks = 0; ks < 2; ++ks) {
      qufr[Mt][ks] = *(const short8*)(quP + (size_t)(i0 + 16 * Mt + m16) * 64 + ks * 32 + koff0);
#pragma unroll
      for (int off = 0; off < 2; ++off)
        qvfr[off][Mt][ks] =
            *(const short8*)(qvP + (size_t)(i0 + off + 16 * Mt + m16) * 64 + ks * 32 + koff0);
    }

  if (tid < 32) { mrow[tid] = -3.0e38f; lrow[tid] = 0.f; arow[tid] = 0.f; }

  f32x4 ctx0 = {0.f, 0.f, 0.f, 0.f}, ctx1 = {0.f, 0.f, 0.f, 0.f};

  const ushort* ksP = Ksw + (size_t)ph * KPL;
  const ushort* vsP = Vsw + (size_t)ph * VPL;
  const ushort* psP = Psw + (size_t)ph * PPL;

  for (int j0 = 0; j0 < L; j0 += 64) {
    __syncthreads();

    const int jt = j0 >> 6;
    const int A1 = L - 32 - i0 + j0, A2 = j0 - i0 - 33;
    const int ro1 = A1 + PADLO, ro2 = A2 + PADLO;
    const int rb1 = ro1 >> 4, rb2 = ro2 >> 4;
    const int d1 = ro1 & 15, d2 = ro2 & 15;

    {
      const ushort* kgo = ksP + (size_t)jt * 4096;
      const ushort* vgo = vsP + (size_t)jt * 4096;
      const ushort* p1o = psP + (size_t)rb1 * 1024;
      const ushort* p2o = psP + (size_t)rb2 * 1024;
      for (int t = wave; t < 44; t += 4) {
        const ushort* g;
        int l;
        if (t < 8)       { g = kgo + t * 512;        l = t * 512; }
        else if (t < 16) { g = vgo + (t - 8) * 512;  l = 4096 + (t - 8) * 512; }
        else if (t < 30) { g = p1o + (t - 16) * 512; l = 8192 + (t - 16) * 512; }
        else             { g = p2o + (t - 30) * 512; l = 15360 + (t - 30) * 512; }
        __builtin_amdgcn_global_load_lds((gas_t)(g + lane * 8), (las_t)(SMEM + l), 16, 0, 0);
      }
    }
    __syncthreads();

    const int jrem = L - j0;
    const int jmax = (jrem < 64) ? jrem : 64;
    const int cthr = 31 + i0 - j0;

    f32x4 av[9];
#pragma unroll
    for (int t = 0; t < 9; ++t) {
      const int id = wave + 4 * t;
      f32x4 a = {0.f, 0.f, 0.f, 0.f};
      if (id < 8) {
        const int Mt = id & 1, Nt = id >> 1;
        if (16 * Nt < jmax) {
          const ushort* bp = Ks_ + (Nt * 2) * 512 + lane * 8;
          a = __builtin_amdgcn_mfma_f32_16x16x32_bf16(qufr[Mt][0], *(const short8*)bp, a, 0, 0, 0);
          a = __builtin_amdgcn_mfma_f32_16x16x32_bf16(qufr[Mt][1], *(const short8*)(bp + 512), a, 0, 0, 0);
        }
      } else if (id < 22) {
        const int e = id - 8, Mt = e & 1, Ntp = e >> 1;
        const int sm = 16 * (Ntp + Mt);
        if (sm >= d1 + 1 && sm <= jmax + d1 + 30 && 16 * Ntp - d1 <= cthr) {
          const ushort* bp = P1s_ + (Ntp * 2) * 512 + lane * 8;
          a = __builtin_amdgcn_mfma_f32_16x16x32_bf16(qvfr[0][Mt][0], *(const short8*)bp, a, 0, 0, 0);
          a = __builtin_amdgcn_mfma_f32_16x16x32_bf16(qvfr[0][Mt][1], *(const short8*)(bp + 512), a, 0, 0, 0);
        }
      } else {
        const int e = id - 22, Mt = e & 1, Ntp = e >> 1;
        const int sm = 16 * (Ntp + Mt);
        if (sm >= d2 + 1 && sm <= jmax + d2 + 30 && 16 * Ntp + 15 - d2 > cthr) {
          const ushort* bp = P2s_ + (Ntp * 2) * 512 + lane * 8;
          a = __builtin_amdgcn_mfma_f32_16x16x32_bf16(qvfr[1][Mt][0], *(const short8*)bp, a, 0, 0, 0);
          a = __builtin_amdgcn_mfma_f32_16x16x32_bf16(qvfr[1][Mt][1], *(const short8*)(bp + 512), a, 0, 0, 0);
        }
      }
      av[t] = a;
    }
    __syncthreads();

#pragma unroll
    for (int t = 0; t < 9; ++t) {
      const int id = wave + 4 * t;
      if (id < 8) {
        const int Mt = id & 1, Nt = id >> 1;
        if (16 * Nt < jmax) {
#pragma unroll
          for (int reg = 0; reg < 4; ++reg)
            sc[(16 * Mt + quad * 4 + reg) * 68 + 16 * Nt + m16] = av[t][reg];
        }
      }
    }
    __syncthreads();

#pragma unroll
    for (int t = 0; t < 9; ++t) {
      const int id = wave + 4 * t;
      if (id >= 8) {
        const bool isG2 = id >= 22;
        const int e = id - (isG2 ? 22 : 8), Mt = e & 1, Ntp = e >> 1;
        const int dl = isG2 ? d2 : d1;
        const int sm = 16 * (Ntp + Mt);
        const bool use = sm >= dl + 1 && sm <= jmax + dl + 30 &&
                         (isG2 ? (16 * Ntp + 15 - dl > cthr) : (16 * Ntp - dl <= cthr));
        if (use) {
          const int c = 16 * Ntp + m16 - dl;
          const bool sel = isG2 ? (c > cthr) : (c <= cthr);
          if (sel) {
#pragma unroll
            for (int reg = 0; reg < 4; ++reg) {
              const int il = 16 * Mt + quad * 4 + reg;
              const int jl = c - 31 + il;
              if (jl >= 0 && jl < 64) sc[il * 68 + jl] += av[t][reg];
            }
          }
        }
      }
    }
    __syncthreads();

    {
      const int row = tid >> 3, t8 = tid & 7, jb = t8 * 8;
      const float* sr = sc + row * 68 + jb;
      float mx = -3.0e38f;
#pragma unroll
      for (int q = 0; q < 8; ++q)
        if (jb + q < jmax) mx = fmaxf(mx, sr[q]);
#pragma unroll
      for (int off = 1; off < 8; off <<= 1)
        mx = fmaxf(mx, __shfl_xor(mx, off, 64));
      if (t8 == 0) {
        const float mo = mrow[row];
        const float mn = fmaxf(mo, mx);
        arow[row] = __expf((mo - mn) * OOS);
        mrow[row] = mn;
      }
    }
    __syncthreads();
    {
      const int row = tid >> 3, t8 = tid & 7, jb = t8 * 8;
      const float m = mrow[row];
      const float* sr = sc + row * 68 + jb;
      float e[8], s = 0.f;
#pragma unroll
      for (int q = 0; q < 8; ++q) {
        float v = 0.f;
        if (jb + q < jmax) v = __expf((sr[q] - m) * OOS);
        e[q] = v;
        s += v;
      }
      ushort4 u0, u1;
      u0.x = f2bf(e[0]); u0.y = f2bf(e[1]); u0.z = f2bf(e[2]); u0.w = f2bf(e[3]);
      u1.x = f2bf(e[4]); u1.y = f2bf(e[5]); u1.z = f2bf(e[6]); u1.w = f2bf(e[7]);
      *(ushort4*)&Pb[row * 72 + jb] = u0;
      *(ushort4*)&Pb[row * 72 + jb + 4] = u1;
#pragma unroll
      for (int off = 1; off < 8; off <<= 1) s += __shfl_xor(s, off, 64);
      if (t8 == 0) lrow[row] = lrow[row] * arow[row] + s;
    }
    __syncthreads();

    {
      float al[4];
#pragma unroll
      for (int reg = 0; reg < 4; ++reg) al[reg] = arow[16 * mw + quad * 4 + reg];
#pragma unroll
      for (int reg = 0; reg < 4; ++reg) { ctx0[reg] *= al[reg]; ctx1[reg] *= al[reg]; }
      const ushort* ap = Pb + (16 * mw + m16) * 72;
#pragma unroll
      for (int ksj = 0; ksj < 2; ++ksj) {
        const short8 a = *(const short8*)(ap + ksj * 32 + koff0);
        ctx0 = __builtin_amdgcn_mfma_f32_16x16x32_bf16(
            a, *(const short8*)(Vts_ + ((nw * 2) * 2 + ksj) * 512 + lane * 8), ctx0, 0, 0, 0);
        ctx1 = __builtin_amdgcn_mfma_f32_16x16x32_bf16(
            a, *(const short8*)(Vts_ + ((nw * 2 + 1) * 2 + ksj) * 512 + lane * 8), ctx1, 0, 0, 0);
      }
    }
  }

#pragma unroll
  for (int reg = 0; reg < 4; ++reg) {
    const int il = 16 * mw + quad * 4 + reg;
    const int gi = i0 + il;
    const float inv = (gi < L) ? (1.f / lrow[il]) : 0.f;
    CTX[gb + (size_t)gi * D_ + nw * 32 + m16]      = ctx0[reg] * inv;
    CTX[gb + (size_t)gi * D_ + nw * 32 + 16 + m16] = ctx1[reg] * inv;
  }
}

// ---------------------------------------------------------------------------
extern "C" void kernel_launch(void* const* d_in, const int* in_sizes, int n_in,
                              void* d_out, int out_size, void* d_ws, size_t ws_size,
                              hipStream_t stream)
{
  (void)in_sizes; (void)n_in; (void)out_size;
  const float* query = (const float*)d_in[0];
  const float* key   = (const float*)d_in[1];
  const float* value = (const float*)d_in[2];
  const float* pos   = (const float*)d_in[3];
  const float* Wq    = (const float*)d_in[4];
  const float* bq    = (const float*)d_in[5];
  const float* Wk    = (const float*)d_in[6];
  const float* bk    = (const float*)d_in[7];
  const float* Wv    = (const float*)d_in[8];
  const float* bv    = (const float*)d_in[9];
  const float* Wpos  = (const float*)d_in[10];
  const float* ub    = (const float*)d_in[11];
  const float* vb    = (const float*)d_in[12];
  const float* Wout  = (const float*)d_in[13];
  const float* bout  = (const float*)d_in[14];
  const int*   mask  = (const int*)d_in[15];

  char* cur = (char*)d_ws;
  auto take = [&](size_t bytes) {
    char* p = cur;
    cur += (bytes + 255) & ~(size_t)255;
    return p;
  };
  float*  CTX = (float*)take((size_t)4096 * 1024 * 4);
  ushort* Qu  = (ushort*)take((size_t)64 * QPL * 2);
  ushort* Qv  = (ushort*)take((size_t)64 * QPL * 2);
  ushort* Ksw = (ushort*)take((size_t)64 * KPL * 2);
  ushort* Vsw = (ushort*)take((size_t)64 * VPL * 2);
  ushort* Psw = (ushort*)take((size_t)64 * PPL * 2);
  ushort* Ah[4], *Al[4];
  for (int i = 0; i < 4; ++i) {
    Ah[i] = (ushort*)take((size_t)APL_SW * 2);
    Al[i] = (ushort*)take((size_t)APL_SW * 2);
  }
  ushort* Wh[5], *Wl[5];
  for (int i = 0; i < 5; ++i) {
    Wh[i] = (ushort*)take((size_t)WPL_SW * 2);
    Wl[i] = (ushort*)take((size_t)WPL_SW * 2);
  }
  int* len = (int*)take(256);
  // CTX hi/lo alias the (then-dead) query activation planes
  ushort* Ch = Ah[0];
  ushort* Cl = Al[0];
  if (ws_size < (size_t)(cur - (char*)d_ws)) return;

  len_kernel<<<dim3(B_), dim3(256), 0, stream>>>(mask, len, Psw);

  // fp32 -> swizzled hi/lo bf16 conversions
  {
    ConvArgs a;
    a.d[0] = {query, Ah[0], Al[0]};
    a.d[1] = {key,   Ah[1], Al[1]};
    a.d[2] = {value, Ah[2], Al[2]};
    a.d[3] = {pos,   Ah[3], Al[3]};
    a.d[4] = {query, Ah[0], Al[0]};  // unused
    conv_split<<<dim3(256, 4), dim3(256), 0, stream>>>(a);
    ConvArgs w;
    w.d[0] = {Wq,   Wh[0], Wl[0]};
    w.d[1] = {Wk,   Wh[1], Wl[1]};
    w.d[2] = {Wv,   Wh[2], Wl[2]};
    w.d[3] = {Wpos, Wh[3], Wl[3]};
    w.d[4] = {Wout, Wh[4], Wl[4]};
    conv_split<<<dim3(64, 5), dim3(256), 0, stream>>>(w);
  }

  const dim3 gblk(256), ggrid(1024 / 128, 4096 / 64);  // (8, 64)
  gemm_bf16x3<1><<<ggrid, gblk, 0, stream>>>(Ah[0], Al[0], Wh[0], Wl[0], bq, nullptr,
                                             Qu, Qv, ub, vb);
  gemm_bf16x3<2><<<ggrid, gblk, 0, stream>>>(Ah[1], Al[1], Wh[1], Wl[1], bk, nullptr,
                                             Ksw, nullptr, nullptr, nullptr);
  gemm_bf16x3<3><<<ggrid, gblk, 0, stream>>>(Ah[2], Al[2], Wh[2], Wl[2], bv, nullptr,
                                             Vsw, nullptr, nullptr, nullptr);
  gemm_bf16x3<4><<<ggrid, gblk, 0, stream>>>(Ah[3], Al[3], Wh[3], Wl[3], nullptr, nullptr,
                                             Psw, nullptr, nullptr, nullptr);

  attn_mfma2<<<dim3(S_ / 32, H_, B_), dim3(256), 0, stream>>>(
      Qu, Qv, Ksw, Vsw, Psw, len, CTX);

  {
    ConvArgs c;
    c.d[0] = {CTX, Ch, Cl};
    c.d[1] = c.d[0]; c.d[2] = c.d[0]; c.d[3] = c.d[0]; c.d[4] = c.d[0];
    conv_split<<<dim3(256, 1), dim3(256), 0, stream>>>(c);
  }

  gemm_bf16x3<0><<<ggrid, gblk, 0, stream>>>(Ch, Cl, Wh[4], Wl[4], bout, (float*)d_out,
                                             nullptr, nullptr, nullptr, nullptr);
}